// Round 1
// 218.330 us; speedup vs baseline: 1.0510x; 1.0510x over previous
//
#include <hip/hip_runtime.h>
#include <math.h>

#define BB 2
#define SS 2048
#define DD 1024
#define HH 16
#define DKK 64
#define MM (BB * SS) /* 4096 */
#define KK DD        /* GEMM K = 1024 */
#define VSTR 2176    /* Vt row stride in shorts (4352 B) — breaks 4 KB channel aliasing */

typedef __attribute__((ext_vector_type(8))) short short8;
typedef __attribute__((ext_vector_type(4))) float floatx4;

__device__ inline unsigned short f2bf(float x) {
    unsigned int u = __float_as_uint(x);
    u += 0x7fffu + ((u >> 16) & 1u);   // round to nearest even
    return (unsigned short)(u >> 16);
}

// pack two fp32 -> bf16x2 dword (truncating): lo from a, hi from b
__device__ inline unsigned int pkbf(float a, float b) {
    return (__float_as_uint(b) & 0xffff0000u) | (__float_as_uint(a) >> 16);
}

__device__ inline void cast4f(const float* __restrict__ in, unsigned short* __restrict__ out, int i) {
    const float4 v = *(const float4*)(in + i);
    unsigned long long pk = (unsigned long long)f2bf(v.x)
                          | ((unsigned long long)f2bf(v.y) << 16)
                          | ((unsigned long long)f2bf(v.z) << 32)
                          | ((unsigned long long)f2bf(v.w) << 48);
    *(unsigned long long*)(out + i) = pk;
}

// single fused cast dispatch: blocks 0..12287 -> q/k/v (4096 each); 12288..16383 -> weights (1024 each)
__global__ __launch_bounds__(256) void cast_all(const float* __restrict__ q, const float* __restrict__ k,
                                                const float* __restrict__ v,
                                                const float* __restrict__ wq, const float* __restrict__ wk,
                                                const float* __restrict__ wv, const float* __restrict__ wo,
                                                unsigned short* __restrict__ oq, unsigned short* __restrict__ ok,
                                                unsigned short* __restrict__ ov,
                                                unsigned short* __restrict__ owq, unsigned short* __restrict__ owk,
                                                unsigned short* __restrict__ owv, unsigned short* __restrict__ owo) {
    const int blk = blockIdx.x;
    const float* in;
    unsigned short* out;
    int idx;
    if (blk < 12288) {
        const int w = blk >> 12;            // /4096
        idx = blk & 4095;
        in  = (w == 0) ? q : (w == 1) ? k : v;
        out = (w == 0) ? oq : (w == 1) ? ok : ov;
    } else {
        const int w = (blk - 12288) >> 10;  // /1024
        idx = (blk - 12288) & 1023;
        in  = (w == 0) ? wq : (w == 1) ? wk : (w == 2) ? wv : wo;
        out = (w == 0) ? owq : (w == 1) ? owk : (w == 2) ? owv : owo;
    }
    cast4f(in, out, (idx * 256 + threadIdx.x) * 4);
}

#define GLDS(gp, lp) __builtin_amdgcn_global_load_lds( \
    (const __attribute__((address_space(1))) void*)(gp), \
    (__attribute__((address_space(3))) void*)(lp), 16, 0, 0)

#define SCHED0() __builtin_amdgcn_sched_barrier(0)
#define BAR()    __builtin_amdgcn_s_barrier()
#define WAITL0() asm volatile("s_waitcnt lgkmcnt(0)" ::: "memory")
#define WAITV(n) asm volatile("s_waitcnt vmcnt(" #n ")" ::: "memory")

// ============================================================================
// Counted-vmcnt dbuf GEMM mainloop (T3+T4+T5+T2), BK=64, 512 threads = 8 waves
// (2 M-waves x 4 N-waves). Tile = (MT*128) x 256. Per wave: (MT*64) x 64.
//
// Schedule per K-tile t (p = t&1):
//   ds_read all frags of buf[p] (24/16 x b128, XOR-swizzled: 2-way max)
//   MFMA k-slice 0
//   lgkmcnt(0); sched_barrier; s_barrier      <- all waves DONE READING buf[p]
//   stage K-tile t+2 -> buf[p]                <- writes cannot land before bar
//   setprio(1); MFMA k-slice 1; setprio(0)    <- hides staging issue
//   vmcnt(8/6)  [NEVER 0 in steady state]     <- retire t+1's loads, keep t+2's
//   s_barrier                                 <- buf[p^1] ready for next iter
// Each K-tile's loads get a full iteration (~1200 cyc) of latency hiding.
// ============================================================================
template<int MT>
__device__ __forceinline__ void gemm_mainloop(const unsigned short* __restrict__ A,
                                              const unsigned short* __restrict__ W,
                                              int m0, int n0,
                                              unsigned short* __restrict__ As,
                                              unsigned short* __restrict__ Bs,
                                              floatx4 (&acc)[MT * 4][4]) {
    const int t    = threadIdx.x;
    const int lane = t & 63;
    const int wave = t >> 6;
    const int col  = lane & 15;
    const int quad = lane >> 4;
    const int wr   = wave >> 2;          // 0..1
    const int wc   = wave & 3;           // 0..3
    const int wm   = wr * (MT * 64);
    const int wn   = wc * 64;

    // staging: thread t writes 16 B at linear LDS offset t*16 within each 8 KB
    // round -> row = g*64 + (t>>3), phys seg = t&7. Pre-swizzle the GLOBAL
    // source seg by row&7 (involution) so reads can de-swizzle.
    const int r   = t >> 3;
    const int cs  = t & 7;
    const int ksw = (cs ^ (r & 7)) * 8;

    // fragment read segs: row&7 == col&7 for all fragment rows
    const int sA0 = (quad ^ (col & 7)) * 8;        // k-slice 0 (k 0..31)
    const int sA1 = ((quad + 4) ^ (col & 7)) * 8;  // k-slice 1 (k 32..63)

    auto stage = [&](int kt, int pb) {
        const int k0 = kt * 64;
        #pragma unroll
        for (int g = 0; g < 2 * MT; ++g)
            GLDS(A + (size_t)(m0 + g * 64 + r) * KK + k0 + ksw,
                 &As[pb * (MT * 128 * 64) + (g * 64 + r) * 64 + cs * 8]);
        #pragma unroll
        for (int g = 0; g < 4; ++g)
            GLDS(W + (size_t)(n0 + g * 64 + r) * KK + k0 + ksw,
                 &Bs[pb * (256 * 64) + (g * 64 + r) * 64 + cs * 8]);
    };

    stage(0, 0);
    stage(1, 1);
    if constexpr (MT == 2) { WAITV(8); } else { WAITV(6); }
    SCHED0(); BAR(); SCHED0();

    const int NK = KK / 64;  // 16
    for (int kt = 0; kt < NK; ++kt) {
        const int p = kt & 1;
        const unsigned short* Ab = &As[p * (MT * 128 * 64)];
        const unsigned short* Bb = &Bs[p * (256 * 64)];

        short8 a0[MT * 4], a1[MT * 4], b0[4], b1[4];
        #pragma unroll
        for (int i = 0; i < MT * 4; ++i) {
            const unsigned short* ar = Ab + (wm + i * 16 + col) * 64;
            a0[i] = *(const short8*)(ar + sA0);
            a1[i] = *(const short8*)(ar + sA1);
        }
        #pragma unroll
        for (int j = 0; j < 4; ++j) {
            const unsigned short* br = Bb + (wn + j * 16 + col) * 64;
            b0[j] = *(const short8*)(br + sA0);
            b1[j] = *(const short8*)(br + sA1);
        }

        #pragma unroll
        for (int i = 0; i < MT * 4; ++i)
            #pragma unroll
            for (int j = 0; j < 4; ++j)
                acc[i][j] = __builtin_amdgcn_mfma_f32_16x16x32_bf16(a0[i], b0[j], acc[i][j], 0, 0, 0);

        WAITL0(); SCHED0();   // all ds_reads of buf[p] complete (incl. a1/b1)
        BAR(); SCHED0();      // all waves done reading buf[p]

        if (kt + 2 < NK) stage(kt + 2, p);   // safe: issued post-barrier

        __builtin_amdgcn_s_setprio(1);
        #pragma unroll
        for (int i = 0; i < MT * 4; ++i)
            #pragma unroll
            for (int j = 0; j < 4; ++j)
                acc[i][j] = __builtin_amdgcn_mfma_f32_16x16x32_bf16(a1[i], b1[j], acc[i][j], 0, 0, 0);
        __builtin_amdgcn_s_setprio(0);

        if (kt + 2 < NK) {
            if constexpr (MT == 2) { WAITV(8); } else { WAITV(6); }  // t+1 retired, t+2 in flight
        } else {
            WAITV(0);                                               // epilogue drain (once)
        }
        SCHED0(); BAR(); SCHED0();   // buf[p^1] ready for next iteration
    }
}

// ---------- fused Q/K/V projections: 256x256 tiles, 192 blocks ----------
__global__ __launch_bounds__(512, 2) void gemm_qkv(const unsigned short* __restrict__ qB,
                                                   const unsigned short* __restrict__ kB,
                                                   const unsigned short* __restrict__ vB,
                                                   const unsigned short* __restrict__ wqB,
                                                   const unsigned short* __restrict__ wkB,
                                                   const unsigned short* __restrict__ wvB,
                                                   const float* __restrict__ bq,
                                                   const float* __restrict__ bk,
                                                   const float* __restrict__ bv,
                                                   unsigned short* __restrict__ Qh,
                                                   unsigned short* __restrict__ Kh,
                                                   unsigned short* __restrict__ Vt) {
    __shared__ __align__(16) unsigned short As[2 * 256 * 64];   // 64 KB
    __shared__ __align__(16) unsigned short Bs[2 * 256 * 64];   // 64 KB

    // bijective XCD swizzle: 192 blocks, 24/XCD -> same-GEMM same-n tiles share L2
    const int bid   = blockIdx.x;
    const int wgid  = (bid & 7) * 24 + (bid >> 3);
    const int which = wgid >> 6;           // 0=Q 1=K 2=V
    const int tile  = wgid & 63;
    const int m0    = (tile & 15) * 256;
    const int n0    = (tile >> 4) * 256;

    const unsigned short* A = (which == 0) ? qB : (which == 1) ? kB : vB;
    const unsigned short* W = (which == 0) ? wqB : (which == 1) ? wkB : wvB;
    const float* bias       = (which == 0) ? bq : (which == 1) ? bk : bv;

    floatx4 acc[8][4] = {};
    gemm_mainloop<2>(A, W, m0, n0, As, Bs, acc);

    const int t    = threadIdx.x;
    const int lane = t & 63;
    const int wave = t >> 6;
    const int col  = lane & 15;
    const int quad = lane >> 4;
    const int wm   = (wave >> 2) * 128;
    const int wn   = (wave & 3) * 64;

    #pragma unroll
    for (int i = 0; i < 8; ++i) {
        #pragma unroll
        for (int j = 0; j < 4; ++j) {
            const int n  = n0 + wn + j * 16 + col;
            const float bv0 = bias[n];
            const int h = n >> 6, dk = n & 63;
            const int mb  = m0 + wm + i * 16 + quad * 4;
            const int bdx = mb >> 11, s = mb & 2047;
            if (which != 2) {
                unsigned short* O = (which == 0) ? Qh : Kh;
                #pragma unroll
                for (int rr = 0; rr < 4; ++rr)
                    O[(((size_t)(bdx * HH + h)) * SS + (s + rr)) * DKK + dk] = f2bf(acc[i][j][rr] + bv0);
            } else {
                // transposed store: 4 consecutive s -> packed uint2 (rounded)
                unsigned short* vp = Vt + (((size_t)(bdx * HH + h)) * DKK + dk) * VSTR + s;
                uint2 w;
                w.x = (unsigned int)f2bf(acc[i][j][0] + bv0) | ((unsigned int)f2bf(acc[i][j][1] + bv0) << 16);
                w.y = (unsigned int)f2bf(acc[i][j][2] + bv0) | ((unsigned int)f2bf(acc[i][j][3] + bv0) << 16);
                *(uint2*)vp = w;
            }
        }
    }
}

// ---------- output projection: 128x256 tiles, 128 blocks ----------
__global__ __launch_bounds__(512, 2) void gemm_out(const unsigned short* __restrict__ A,
                                                   const unsigned short* __restrict__ W,
                                                   const float* __restrict__ bias,
                                                   float* __restrict__ C) {
    __shared__ __align__(16) unsigned short As[2 * 128 * 64];   // 32 KB
    __shared__ __align__(16) unsigned short Bs[2 * 256 * 64];   // 64 KB

    const int bid  = blockIdx.x;
    const int wgid = (bid & 7) * 16 + (bid >> 3);   // 128 blocks, 16/XCD
    const int m0   = (wgid & 31) * 128;
    const int n0   = (wgid >> 5) * 256;

    floatx4 acc[4][4] = {};
    gemm_mainloop<1>(A, W, m0, n0, As, Bs, acc);

    const int t    = threadIdx.x;
    const int lane = t & 63;
    const int wave = t >> 6;
    const int col  = lane & 15;
    const int quad = lane >> 4;
    const int wm   = (wave >> 2) * 64;
    const int wn   = (wave & 3) * 64;

    #pragma unroll
    for (int i = 0; i < 4; ++i) {
        #pragma unroll
        for (int j = 0; j < 4; ++j) {
            const int n = n0 + wn + j * 16 + col;
            const float bv0 = bias[n];
            #pragma unroll
            for (int rr = 0; rr < 4; ++rr) {
                const int m = m0 + wm + i * 16 + quad * 4 + rr;
                C[(size_t)m * DD + n] = acc[i][j][rr] + bv0;
            }
        }
    }
}

// ---------- attention ----------
#define C1 0.18033688011112042f   /* 0.125 * log2(e) */
#define C2 11.541560327111707f    /* 8 * log2(e)     */
#define MFMA __builtin_amdgcn_mfma_f32_16x16x32_bf16

// S^T-oriented GEMM-style flash attention.
// One block = 64 consecutive queries (4 waves x 16 q). K/V staged block-wide into
// dbuf LDS (BK=64 keys/barrier) via global_load_lds, XOR-swizzled segs.
// S^T = K*Q^T puts 4 consecutive keys per lane -> P^T pack = 2 ds_write_b64,
// PV = V^T * P^T with one b128 P read; output O^T packs to b64 stores.
__global__ __launch_bounds__(256) void attn_mfma(const unsigned short* __restrict__ Qh,
                                                 const unsigned short* __restrict__ Kh,
                                                 const unsigned short* __restrict__ Vt,
                                                 unsigned short* __restrict__ X) {
    __shared__ __align__(16) unsigned short Ks[2][64 * 64];   // [key][dim], swizzled segs
    __shared__ __align__(16) unsigned short Vs[2][64 * 64];   // [dim][key], swizzled segs
    __shared__ __align__(16) unsigned short Plds[4][16 * 40]; // [q][key], stride 40 shorts

    const int t    = threadIdx.x;
    const int lane = t & 63;
    const int wave = t >> 6;
    const int col  = lane & 15;
    const int quad = lane >> 4;

    // xcd = lin&7 (heads {x,x+8,x+16,x+24} per xcd); chunks descending (longest first)
    const int lin = blockIdx.x;                    // 0..1023
    const int bh  = (lin & 7) + 8 * ((lin >> 3) & 3);
    const int c   = 31 - (lin >> 5);               // chunk of 64 queries
    const int b   = bh / HH, h = bh % HH;

    const unsigned short* Kb = Kh + (size_t)bh * SS * DKK;
    const unsigned short* Vb = Vt + (size_t)bh * DKK * VSTR;

    // staging positions p0 = t, p1 = t+256: row = p>>3, phys seg = p&7,
    // source seg = (p&7) ^ (row&7)  (same swizzle for K and V)
    const int r0  = t >> 3;
    const int r1  = (t + 256) >> 3;
    const int sg0 = ((t & 7) ^ (r0 & 7)) * 8;
    const int sg1 = ((t & 7) ^ (r1 & 7)) * 8;

    const int q0 = c * 64 + wave * 16;
    unsigned short* Pw = &Plds[wave][0];

    const unsigned short* Qb = Qh + ((size_t)bh * SS + q0) * DKK;
    const short8 qa0 = *(const short8*)(Qb + (size_t)col * DKK + quad * 8);
    const short8 qa1 = *(const short8*)(Qb + (size_t)col * DKK + 32 + quad * 8);

    floatx4 o0 = {0.f, 0.f, 0.f, 0.f}, o1 = o0, o2 = o0, o3 = o0;
    float lp = 0.f;

    const int nst = c + 1;                          // 64-key steps

    // fragment read seg offsets (must match staging swizzle)
    const int ksA = ((quad)      ^ (col & 7)) * 8;  // dims/keys seg quad
    const int ksB = ((quad | 4)  ^ (col & 7)) * 8;  // seg quad+4

    // prologue: stage step 0 into buf 0
    GLDS(Kb + (size_t)r0 * DKK + sg0,  &Ks[0][t * 8]);
    GLDS(Kb + (size_t)r1 * DKK + sg1,  &Ks[0][(t + 256) * 8]);
    GLDS(Vb + (size_t)r0 * VSTR + sg0, &Vs[0][t * 8]);
    GLDS(Vb + (size_t)r1 * VSTR + sg1, &Vs[0][(t + 256) * 8]);

    int cur = 0;
    for (int kb = 0; kb < nst; ++kb) {
        __syncthreads();

        if (kb + 1 < nst) {
            const int jn = (kb + 1) * 64;
            const int nx = cur ^ 1;
            GLDS(Kb + (size_t)(jn + r0) * DKK + sg0,  &Ks[nx][t * 8]);
            GLDS(Kb + (size_t)(jn + r1) * DKK + sg1,  &Ks[nx][(t + 256) * 8]);
            GLDS(Vb + (size_t)r0 * VSTR + jn + sg0,   &Vs[nx][t * 8]);
            GLDS(Vb + (size_t)r1 * VSTR + jn + sg1,   &Vs[nx][(t + 256) * 8]);
        }

        const unsigned short* Kp = &Ks[cur][0];
        const unsigned short* Vp = &Vs[cur][0];

        #pragma unroll
        for (int hh = 0; hh < 2; ++hh) {
            const int j0 = kb * 64 + hh * 32;
            if (j0 < q0 + 16) {
                // S^T tiles: keys j0+0..15 (t0) and j0+16..31 (t1); A=K rows, B=Q
                const short8 k0 = *(const short8*)(Kp + (hh * 32 + col) * 64 + ksA);
                const short8 k1 = *(const short8*)(Kp + (hh * 32 + col) * 64 + ksB);
                const short8 k2 = *(const short8*)(Kp + (hh * 32 + col + 16) * 64 + ksA);
                const short8 k3 = *(const short8*)(Kp + (hh * 32 + col + 16) * 64 + ksB);

                floatx4 t0 = {0.f, 0.f, 0.f, 0.f}, t1 = t0;
                t0 = MFMA(k0, qa0, t0, 0, 0, 0);
                t0 = MFMA(k1, qa1, t0, 0, 0, 0);
                t1 = MFMA(k2, qa0, t1, 0, 0, 0);
                t1 = MFMA(k3, qa1, t1, 0, 0, 0);

                // lane (col=q, quad) holds keys j0+quad*4+r (t0), j0+16+quad*4+r (t1)
                float p[8];
                if (j0 + 31 > q0) {   // diagonal: per-lane mask
                    const int lim = q0 + col - j0;   // keys rel <= lim pass
                    #pragma unroll
                    for (int r = 0; r < 4; ++r) {
                        p[r]     = (quad * 4 + r      <= lim) ? __builtin_exp2f(fmaf(t0[r], C1, -C2)) : 0.f;
                        p[4 + r] = (16 + quad * 4 + r <= lim) ? __builtin_exp2f(fmaf(t1[r], C1, -C2)) : 0.f;
                    }
                } else {
                    #pragma unroll
                    for (int r = 0; r < 4; ++r) {
                        p[r]     = __builtin_exp2f(fmaf(t0[r], C1, -C2));
                        p[4 + r] = __builtin_exp2f(fmaf(t1[r], C1, -C2));
                    }
                }
                lp += (p[0] + p[1]) + (p[2] + p[3]) + (p[4] + p[5]) + (p[6] + p[7]);

                // P^T -> LDS: keys rel quad*4..+3 and 16+quad*4..+3 of row q=col
                uint2 w0 = { pkbf(p[0], p[1]), pkbf(p[2], p[3]) };
                uint2 w1 = { pkbf(p[4], p[5]), pkbf(p[6], p[7]) };
                *(uint2*)(Pw + col * 40 + quad * 4)      = w0;
                *(uint2*)(Pw + col * 40 + 16 + quad * 4) = w1;

                // PV: A = V^T (dim rows), B = P^T (one b128, keys quad*8..+7 of q=col)
                const short8 pb = *(const short8*)(Pw + col * 40 + quad * 8);
                const int vs = hh ? ksB : ksA;    // V seg (4*hh+quad)^(col&7)
                const short8 v0 = *(const short8*)(Vp + (col)      * 64 + vs);
                const short8 v1 = *(const short8*)(Vp + (col + 16) * 64 + vs);
                const short8 v2 = *(const short8*)(Vp + (col + 32) * 64 + vs);
                const short8 v3 = *(const short8*)(Vp + (col + 48) * 64 + vs);
                o0 = MFMA(v0, pb, o0, 0, 0, 0);
                o1 = MFMA(v1, pb, o1, 0, 0, 0);
                o2 = MFMA(v2, pb, o2, 0, 0, 0);
                o3 = MFMA(v3, pb, o3, 0, 0, 0);
            }
        }

        cur ^= 1;
    }

    // combine l across quads (lanes col, col+16, col+32, col+48 share q=col)
    lp += __shfl_xor(lp, 16, 64);
    lp += __shfl_xor(lp, 32, 64);
    const float li = 1.f / lp;

    // O^T: lane (col=q, quad) holds dims 16m + quad*4 + r -> 4 packed b64 stores
    unsigned short* Xp = X + ((size_t)(b * SS + q0 + col)) * DD + h * DKK + quad * 4;
    {
        uint2 w;
        w.x = (unsigned int)f2bf(o0[0] * li) | ((unsigned int)f2bf(o0[1] * li) << 16);
        w.y = (unsigned int)f2bf(o0[2] * li) | ((unsigned int)f2bf(o0[3] * li) << 16);
        *(uint2*)(Xp + 0) = w;
        w.x = (unsigned int)f2bf(o1[0] * li) | ((unsigned int)f2bf(o1[1] * li) << 16);
        w.y = (unsigned int)f2bf(o1[2] * li) | ((unsigned int)f2bf(o1[3] * li) << 16);
        *(uint2*)(Xp + 16) = w;
        w.x = (unsigned int)f2bf(o2[0] * li) | ((unsigned int)f2bf(o2[1] * li) << 16);
        w.y = (unsigned int)f2bf(o2[2] * li) | ((unsigned int)f2bf(o2[3] * li) << 16);
        *(uint2*)(Xp + 32) = w;
        w.x = (unsigned int)f2bf(o3[0] * li) | ((unsigned int)f2bf(o3[1] * li) << 16);
        w.y = (unsigned int)f2bf(o3[2] * li) | ((unsigned int)f2bf(o3[3] * li) << 16);
        *(uint2*)(Xp + 48) = w;
    }
}

extern "C" void kernel_launch(void* const* d_in, const int* in_sizes, int n_in,
                              void* d_out, int out_size, void* d_ws, size_t ws_size,
                              hipStream_t stream) {
    const float* query = (const float*)d_in[0];
    const float* key   = (const float*)d_in[1];
    const float* value = (const float*)d_in[2];
    const float* wq    = (const float*)d_in[3];
    const float* bq    = (const float*)d_in[4];
    const float* wk    = (const float*)d_in[5];
    const float* bk    = (const float*)d_in[6];
    const float* wv    = (const float*)d_in[7];
    const float* bv    = (const float*)d_in[8];
    const float* wo    = (const float*)d_in[9];
    const float* bo    = (const float*)d_in[10];

    char* ws = (char*)d_ws;
    const size_t MB = 1024 * 1024;
    unsigned short* qB  = (unsigned short*)(ws);             // bf16 [4096,1024] 8 MB (dead after gemm_qkv)
    unsigned short* kB  = (unsigned short*)(ws + 8 * MB);
    unsigned short* vB  = (unsigned short*)(ws + 16 * MB);
    unsigned short* wqB = (unsigned short*)(ws + 24 * MB);   // bf16 [1024,1024] 2 MB
    unsigned short* wkB = (unsigned short*)(ws + 26 * MB);
    unsigned short* wvB = (unsigned short*)(ws + 28 * MB);
    unsigned short* woB = (unsigned short*)(ws + 30 * MB);
    unsigned short* Qh  = (unsigned short*)(ws + 32 * MB);   // bf16 [B,H,S,DK] 8 MB
    unsigned short* Kh  = (unsigned short*)(ws + 40 * MB);
    unsigned short* Vt  = (unsigned short*)(ws + 48 * MB);   // bf16 [B,H,DK,VSTR] ~8.9 MB
    unsigned short* Xb  = qB;                                // bf16 [B,S,D] reuses qB region

    cast_all<<<16384, 256, 0, stream>>>(query, key, value, wq, wk, wv, wo,
                                        qB, kB, vB, wqB, wkB, wvB, woB);

    gemm_qkv<<<192, 512, 0, stream>>>(qB, kB, vB, wqB, wkB, wvB, bq, bk, bv, Qh, Kh, Vt);

    attn_mfma<<<1024, 256, 0, stream>>>(Qh, Kh, Vt, Xb);

    gemm_out<<<128, 512, 0, stream>>>(Xb, woB, bo, (float*)d_out);
}